// Round 1
// baseline (10240.018 us; speedup 1.0000x reference)
//
#include <hip/hip_runtime.h>
#include <hip/hip_bf16.h>
#include <math.h>
#include <stdint.h>

// Problem constants (B=1)
#define S_LEN 2048
#define D_DIM 4096
#define NHEAD 32
#define HDIM  128

// fake-quant to [-128,127] int-valued float, scale 0.1 (matches jnp.round = half-even)
__device__ __forceinline__ float quant128(float x) {
  return fminf(fmaxf(rintf(x / 0.1f), -128.f), 127.f);
}

// ---------------------------------------------------------------------------
// Tiled GEMM: C[s,o] = (sum_d A[s,d] * W[o,d]) * (0.1f * wsc[o])
//   AMODE 0: A is f32, fake-quantize (-128..127, /0.1) each element on load
//   AMODE 1: A is int8 (already quantized values)
//   OMODE 0: store f32
//   OMODE 1: store int8 fake-quant (-128..127, /0.1)  [used for v]
// Tile 64x64, BK=16, 256 threads, 4x4 accum per thread.
// All integer arithmetic is exact in fp32 (|sum| <= 4096*1024 < 2^23).
// ---------------------------------------------------------------------------
template <int AMODE, int OMODE>
__global__ __launch_bounds__(256) void gemm64(
    const void* __restrict__ Ain, const float* __restrict__ W,
    const float* __restrict__ wsc, void* __restrict__ Cout) {
  constexpr int K = D_DIM;
  constexpr int N = D_DIM;
  __shared__ __align__(16) float As[16][64];
  __shared__ __align__(16) float Bs[16][64];
  const int t = threadIdx.x;
  const int tx = t & 15, ty = t >> 4;
  const int bm = blockIdx.y * 64, bn = blockIdx.x * 64;
  const int lr = t >> 2;        // row/col within tile for staging (0..63)
  const int lk = (t & 3) * 4;   // k offset within tile (0,4,8,12)
  float acc[4][4] = {{0.f, 0.f, 0.f, 0.f}};

  for (int k0 = 0; k0 < K; k0 += 16) {
    if (AMODE == 0) {
      const float* A = (const float*)Ain;
      const float4 a = *(const float4*)(A + (size_t)(bm + lr) * K + k0 + lk);
      As[lk + 0][lr] = quant128(a.x);
      As[lk + 1][lr] = quant128(a.y);
      As[lk + 2][lr] = quant128(a.z);
      As[lk + 3][lr] = quant128(a.w);
    } else {
      const int8_t* A = (const int8_t*)Ain;
      const int w = *(const int*)(A + (size_t)(bm + lr) * K + k0 + lk);
      As[lk + 0][lr] = (float)(int8_t)(w & 0xff);
      As[lk + 1][lr] = (float)(int8_t)((w >> 8) & 0xff);
      As[lk + 2][lr] = (float)(int8_t)((w >> 16) & 0xff);
      As[lk + 3][lr] = (float)(int8_t)(w >> 24);
    }
    const float4 b = *(const float4*)(W + (size_t)(bn + lr) * K + k0 + lk);
    Bs[lk + 0][lr] = b.x;
    Bs[lk + 1][lr] = b.y;
    Bs[lk + 2][lr] = b.z;
    Bs[lk + 3][lr] = b.w;
    __syncthreads();
#pragma unroll
    for (int kk = 0; kk < 16; ++kk) {
      const float4 av = *(const float4*)&As[kk][ty * 4];
      const float4 bv = *(const float4*)&Bs[kk][tx * 4];
      const float ar[4] = {av.x, av.y, av.z, av.w};
      const float br[4] = {bv.x, bv.y, bv.z, bv.w};
#pragma unroll
      for (int i = 0; i < 4; ++i)
#pragma unroll
        for (int j = 0; j < 4; ++j) acc[i][j] = fmaf(ar[i], br[j], acc[i][j]);
    }
    __syncthreads();
  }

  const int colb = bn + tx * 4;
  const float s0 = 0.1f * wsc[colb + 0];
  const float s1 = 0.1f * wsc[colb + 1];
  const float s2 = 0.1f * wsc[colb + 2];
  const float s3 = 0.1f * wsc[colb + 3];
#pragma unroll
  for (int i = 0; i < 4; ++i) {
    const int row = bm + ty * 4 + i;
    const float v0 = acc[i][0] * s0;
    const float v1 = acc[i][1] * s1;
    const float v2 = acc[i][2] * s2;
    const float v3 = acc[i][3] * s3;
    if (OMODE == 0) {
      *(float4*)((float*)Cout + (size_t)row * N + colb) = make_float4(v0, v1, v2, v3);
    } else {
      const int q0 = (int)quant128(v0);
      const int q1 = (int)quant128(v1);
      const int q2 = (int)quant128(v2);
      const int q3 = (int)quant128(v3);
      const int packed =
          (q0 & 0xff) | ((q1 & 0xff) << 8) | ((q2 & 0xff) << 16) | ((q3 & 0xff) << 24);
      *(int*)((int8_t*)Cout + (size_t)row * N + colb) = packed;
    }
  }
}

// ---------------------------------------------------------------------------
// RoPE + int8 fake-quant for q and k.
// grid (S, H, 2): z=0 -> q, z=1 -> k. block = 64 threads (j = 0..63 pair index).
// q'[j]    = x[j]*cos - x[j+64]*sin
// q'[j+64] = x[j+64]*cos + x[j]*sin,  ang = pos * theta^(-j/64)
// ---------------------------------------------------------------------------
__global__ __launch_bounds__(64) void rope_quant(
    const float* __restrict__ qproj, const float* __restrict__ kproj,
    int8_t* __restrict__ q8, int8_t* __restrict__ k8,
    const int* __restrict__ pos_ids) {
  const int s = blockIdx.x, h = blockIdx.y, which = blockIdx.z;
  const int j = threadIdx.x;
  const float* src = which ? kproj : qproj;
  int8_t* dst = which ? k8 : q8;
  const size_t base = (size_t)s * D_DIM + (size_t)h * HDIM;
  const float x1 = src[base + j];
  const float x2 = src[base + j + 64];
  const float posf = (float)pos_ids[s];
  // inv_freq[j] = 10000^(-j/64) = 2^(-j * log2(10000)/64)
  const float inv = exp2f((float)j * -0.20762050593046016f);
  const float ang = posf * inv;
  float si, c;
  sincosf(ang, &si, &c);
  const float r1 = x1 * c - x2 * si;
  const float r2 = x2 * c + x1 * si;
  dst[base + j] = (int8_t)quant128(r1);
  dst[base + j + 64] = (int8_t)quant128(r2);
}

// ---------------------------------------------------------------------------
// Attention, one block per (query row, head). 256 threads.
// scores[k] = (sum_d (q_i*0.1)*(k_i*0.1)) / sqrt(128)   for k <= qi (causal)
// softmax in LDS; out[d] = sum_k p[k]*(v_i*0.1); quantize to int8 (-127..127).
// Masked keys contribute exp(-1e9 - max) == 0 in fp32, so skipping k > qi is
// exact vs the reference's additive -1e9 mask.
// ---------------------------------------------------------------------------
__global__ __launch_bounds__(256) void attn_kernel(
    const int8_t* __restrict__ q8, const int8_t* __restrict__ k8,
    const int8_t* __restrict__ v8, int8_t* __restrict__ o8) {
  const int qi = blockIdx.x, h = blockIdx.y, t = threadIdx.x;
  __shared__ __align__(16) float qs[HDIM];     // q row * 0.1
  __shared__ __align__(16) float sc[S_LEN];    // scores -> exp(score - max)
  __shared__ __align__(16) float red[16];
  __shared__ __align__(16) float part[8][HDIM];

  if (t < HDIM) qs[t] = 0.1f * (float)q8[(size_t)qi * D_DIM + (size_t)h * HDIM + t];
  __syncthreads();

  // ---- scores ----
  const int8_t* kb = k8 + (size_t)h * HDIM;
  for (int k = t; k <= qi; k += 256) {
    const int* kr = (const int*)(kb + (size_t)k * D_DIM);
    float s = 0.f;
#pragma unroll
    for (int c = 0; c < 32; ++c) {
      const int w = kr[c];
      s += qs[c * 4 + 0] * (0.1f * (float)(int8_t)(w & 0xff));
      s += qs[c * 4 + 1] * (0.1f * (float)(int8_t)((w >> 8) & 0xff));
      s += qs[c * 4 + 2] * (0.1f * (float)(int8_t)((w >> 16) & 0xff));
      s += qs[c * 4 + 3] * (0.1f * (float)(int8_t)(w >> 24));
    }
    sc[k] = s / 11.313708498984761f;  // / sqrt(128)
  }
  __syncthreads();

  // ---- softmax: max ----
  float m = -3e38f;
  for (int k = t; k <= qi; k += 256) m = fmaxf(m, sc[k]);
#pragma unroll
  for (int off = 32; off > 0; off >>= 1) m = fmaxf(m, __shfl_down(m, off));
  if ((t & 63) == 0) red[t >> 6] = m;
  __syncthreads();
  if (t == 0) red[8] = fmaxf(fmaxf(red[0], red[1]), fmaxf(red[2], red[3]));
  __syncthreads();
  m = red[8];

  // ---- softmax: exp + sum ----
  float l = 0.f;
  for (int k = t; k <= qi; k += 256) {
    const float p = expf(sc[k] - m);
    sc[k] = p;
    l += p;
  }
#pragma unroll
  for (int off = 32; off > 0; off >>= 1) l += __shfl_down(l, off);
  if ((t & 63) == 0) red[4 + (t >> 6)] = l;
  __syncthreads();  // also makes all sc[] prob writes visible
  if (t == 0) red[9] = (red[4] + red[5]) + (red[6] + red[7]);
  __syncthreads();
  const float L = red[9];

  // ---- out = P @ (V*0.1), k split 8 ways, 4 d's per thread ----
  const int d4 = (t & 31) * 4;
  const int half = t >> 5;
  float a0 = 0.f, a1 = 0.f, a2 = 0.f, a3 = 0.f;
  const int8_t* vb = v8 + (size_t)h * HDIM + d4;
  for (int k = half; k <= qi; k += 8) {
    const int w = *(const int*)(vb + (size_t)k * D_DIM);
    const float p = sc[k];
    a0 += p * (0.1f * (float)(int8_t)(w & 0xff));
    a1 += p * (0.1f * (float)(int8_t)((w >> 8) & 0xff));
    a2 += p * (0.1f * (float)(int8_t)((w >> 16) & 0xff));
    a3 += p * (0.1f * (float)(int8_t)(w >> 24));
  }
  *(float4*)&part[half][d4] = make_float4(a0, a1, a2, a3);
  __syncthreads();

  if (t < HDIM) {
    float o = 0.f;
#pragma unroll
    for (int i = 0; i < 8; ++i) o += part[i][t];
    o /= L;
    // out fake-quant clamps to [-127, 127] (note: NOT -128)
    const float oq = fminf(fmaxf(rintf(o / 0.1f), -127.f), 127.f);
    o8[(size_t)qi * D_DIM + (size_t)h * HDIM + t] = (int8_t)oq;
  }
}

// ---------------------------------------------------------------------------
extern "C" void kernel_launch(void* const* d_in, const int* in_sizes, int n_in,
                              void* d_out, int out_size, void* d_ws, size_t ws_size,
                              hipStream_t stream) {
  (void)in_sizes; (void)n_in; (void)out_size; (void)ws_size;
  const float* hidden = (const float*)d_in[0];
  const float* wq = (const float*)d_in[1];
  const float* wk = (const float*)d_in[2];
  const float* wv = (const float*)d_in[3];
  const float* wo = (const float*)d_in[4];
  const float* sq = (const float*)d_in[5];
  const float* sk = (const float*)d_in[6];
  const float* sv = (const float*)d_in[7];
  const float* so = (const float*)d_in[8];
  // d_in[9] = attention_mask (pure causal -1e9; handled analytically)
  const int* pos = (const int*)d_in[10];
  float* out = (float*)d_out;

  char* ws = (char*)d_ws;
  float* qproj = (float*)ws;                         // 32 MB f32 [S,D]
  float* kproj = (float*)(ws + (32u << 20));         // 32 MB f32 [S,D]
  int8_t* q8 = (int8_t*)(ws + (64u << 20));          // 8 MB
  int8_t* k8 = (int8_t*)(ws + (72u << 20));          // 8 MB
  int8_t* v8 = (int8_t*)(ws + (80u << 20));          // 8 MB
  int8_t* o8 = (int8_t*)(ws + (88u << 20));          // 8 MB   (total 96 MB)

  const dim3 gg(D_DIM / 64, S_LEN / 64), gb(256);
  hipLaunchKernelGGL((gemm64<0, 0>), gg, gb, 0, stream, hidden, wq, sq, qproj);
  hipLaunchKernelGGL((gemm64<0, 0>), gg, gb, 0, stream, hidden, wk, sk, kproj);
  hipLaunchKernelGGL((gemm64<0, 1>), gg, gb, 0, stream, hidden, wv, sv, v8);
  hipLaunchKernelGGL(rope_quant, dim3(S_LEN, NHEAD, 2), dim3(64), 0, stream,
                     qproj, kproj, q8, k8, pos);
  hipLaunchKernelGGL(attn_kernel, dim3(S_LEN, NHEAD), dim3(256), 0, stream,
                     q8, k8, v8, o8);
  hipLaunchKernelGGL((gemm64<1, 0>), gg, gb, 0, stream, o8, wo, so, out);
}

// Round 2
// 939.105 us; speedup vs baseline: 10.9040x; 10.9040x over previous
//
#include <hip/hip_runtime.h>
#include <math.h>
#include <stdint.h>

#define S_LEN 2048
#define D_DIM 4096
#define NHEAD 32
#define HDIM  128

typedef int   v4i __attribute__((ext_vector_type(4)));
typedef float v4f __attribute__((ext_vector_type(4)));
typedef short v8s __attribute__((ext_vector_type(8)));

__device__ __forceinline__ float quant128(float x) {
  return fminf(fmaxf(rintf(x / 0.1f), -128.f), 127.f);
}
__device__ __forceinline__ unsigned short bf16_rne(float f) {
  unsigned u = __float_as_uint(f);
  unsigned r = u + 0x7fffu + ((u >> 16) & 1u);
  return (unsigned short)(r >> 16);
}
__device__ __forceinline__ float bf16f(unsigned short h) {
  return __uint_as_float(((unsigned)h) << 16);
}

// ---------------- prep kernels ----------------
__global__ __launch_bounds__(256) void quant_hidden_k(const float* __restrict__ in,
                                                      int8_t* __restrict__ out) {
  const int idx = blockIdx.x * 256 + threadIdx.x;
  const float4 v = ((const float4*)in)[idx];
  const int q0 = (int)quant128(v.x), q1 = (int)quant128(v.y);
  const int q2 = (int)quant128(v.z), q3 = (int)quant128(v.w);
  ((int*)out)[idx] = (q0 & 0xff) | ((q1 & 0xff) << 8) | ((q2 & 0xff) << 16) | ((q3 & 0xff) << 24);
}

__global__ __launch_bounds__(256) void wconv_k(const float* __restrict__ in,
                                               int8_t* __restrict__ out) {
  const int idx = blockIdx.x * 256 + threadIdx.x;
  const float4 v = ((const float4*)in)[idx];  // int4-valued floats (-8..7), exact
  const int q0 = __float2int_rn(v.x), q1 = __float2int_rn(v.y);
  const int q2 = __float2int_rn(v.z), q3 = __float2int_rn(v.w);
  ((int*)out)[idx] = (q0 & 0xff) | ((q1 & 0xff) << 8) | ((q2 & 0xff) << 16) | ((q3 & 0xff) << 24);
}

__global__ __launch_bounds__(256) void rope_tab_k(const int* __restrict__ pos,
                                                  float* __restrict__ ct,
                                                  float* __restrict__ st) {
  const int idx = blockIdx.x * 256 + threadIdx.x;  // [S][64]
  const int s = idx >> 6, j = idx & 63;
  const float inv = exp2f((float)j * -0.20762050593046016f);  // 10000^(-j/64)
  const float a = (float)pos[s] * inv;
  float si, c;
  sincosf(a, &si, &c);
  ct[idx] = c;
  st[idx] = si;
}

// ---------------------------------------------------------------------------
// int8 MFMA GEMM: C[s,o] = (sum_d A8[s,d]*W8[o,d]) * (0.1*wsc[o])  [exact int32]
// 128x128 tile, BK=64, 256 threads (4 waves). Wave w covers n-cols
// {w*16..+15} and {w*16+64..+79} so RoPE col pairs (j, j+64) live in the
// same lane/reg. m-tiles: all 8. 16 MFMA (i32_16x16x64_i8) per wave per BK.
// OMODE: 0=q(RoPE->int8) 1=k(RoPE->int8) 2=v(int8 value->bf16, [d][s] layout)
//        3=o-proj (f32 out)
// ---------------------------------------------------------------------------
template <int OMODE>
__global__ __launch_bounds__(256) void gemm_i8(
    const int8_t* __restrict__ A8, const int8_t* __restrict__ W8,
    const float* __restrict__ wsc, const float* __restrict__ ctab,
    const float* __restrict__ stab, void* __restrict__ outp) {
  __shared__ __align__(16) int8_t Als[128 * 80];  // pad 64->80: b128 reads 2-way (free)
  __shared__ __align__(16) int8_t Bls[128 * 80];
  const int t = threadIdx.x;
  const int w = t >> 6, lane = t & 63, g = lane >> 4, l15 = lane & 15;
  const int bm = blockIdx.y * 128, bn = blockIdx.x * 128;
  const int srow = t >> 1, soff = (t & 1) * 32;

  v4i acc[8][2];
#pragma unroll
  for (int i = 0; i < 8; ++i) {
    acc[i][0] = (v4i){0, 0, 0, 0};
    acc[i][1] = (v4i){0, 0, 0, 0};
  }

  const int8_t* Aptr = A8 + (size_t)(bm + srow) * D_DIM + soff;
  const int8_t* Bptr = W8 + (size_t)(bn + srow) * D_DIM + soff;
  int8_t* Alw = Als + srow * 80 + soff;
  int8_t* Blw = Bls + srow * 80 + soff;

  for (int k0 = 0; k0 < D_DIM; k0 += 64) {
    const int4 a0 = *(const int4*)(Aptr + k0);
    const int4 a1 = *(const int4*)(Aptr + k0 + 16);
    const int4 b0 = *(const int4*)(Bptr + k0);
    const int4 b1 = *(const int4*)(Bptr + k0 + 16);
    *(int4*)(Alw) = a0;
    *(int4*)(Alw + 16) = a1;
    *(int4*)(Blw) = b0;
    *(int4*)(Blw + 16) = b1;
    __syncthreads();
    const v4i bf0 = *(const v4i*)(Bls + (w * 16 + l15) * 80 + g * 16);
    const v4i bf1 = *(const v4i*)(Bls + (w * 16 + 64 + l15) * 80 + g * 16);
#pragma unroll
    for (int mi = 0; mi < 8; ++mi) {
      const v4i af = *(const v4i*)(Als + (mi * 16 + l15) * 80 + g * 16);
      acc[mi][0] = __builtin_amdgcn_mfma_i32_16x16x64_i8(af, bf0, acc[mi][0], 0, 0, 0);
      acc[mi][1] = __builtin_amdgcn_mfma_i32_16x16x64_i8(af, bf1, acc[mi][1], 0, 0, 0);
    }
    __syncthreads();
  }

  // C/D layout: col = l15 (within n-tile), row = g*4 + reg
  if (OMODE == 0 || OMODE == 1) {
    // RoPE: block spans one head (128 cols). j = in-head col 0..63 (jt=0),
    // pair col j+64 (jt=1). q'[j] = x1*c - x2*s; q'[j+64] = x2*c + x1*s.
    const int jcol = w * 16 + l15;  // 0..63
    const float sc0 = 0.1f * wsc[bn + jcol];
    const float sc1 = 0.1f * wsc[bn + jcol + 64];
    int8_t* dst = (int8_t*)outp;
#pragma unroll
    for (int mi = 0; mi < 8; ++mi) {
#pragma unroll
      for (int r = 0; r < 4; ++r) {
        const int s = bm + mi * 16 + g * 4 + r;
        const float c = ctab[s * 64 + jcol];
        const float si = stab[s * 64 + jcol];
        const float x1 = (float)acc[mi][0][r] * sc0;
        const float x2 = (float)acc[mi][1][r] * sc1;
        dst[(size_t)s * D_DIM + bn + jcol] = (int8_t)quant128(x1 * c - x2 * si);
        dst[(size_t)s * D_DIM + bn + jcol + 64] = (int8_t)quant128(x2 * c + x1 * si);
      }
    }
  } else if (OMODE == 2) {
    // v: int8-valued result stored as bf16 (exact for |v|<=128), layout [col][s]
    unsigned short* dst = (unsigned short*)outp;
#pragma unroll
    for (int jt = 0; jt < 2; ++jt) {
      const int col = bn + w * 16 + jt * 64 + l15;
      const float scv = 0.1f * wsc[col];
#pragma unroll
      for (int mi = 0; mi < 8; ++mi) {
#pragma unroll
        for (int r = 0; r < 4; ++r) {
          const int s = bm + mi * 16 + g * 4 + r;
          const float q = quant128((float)acc[mi][jt][r] * scv);
          dst[(size_t)col * S_LEN + s] = (unsigned short)(__float_as_uint(q) >> 16);
        }
      }
    }
  } else {
    float* dst = (float*)outp;
#pragma unroll
    for (int jt = 0; jt < 2; ++jt) {
      const int col = bn + w * 16 + jt * 64 + l15;
      const float scv = 0.1f * wsc[col];
#pragma unroll
      for (int mi = 0; mi < 8; ++mi) {
#pragma unroll
        for (int r = 0; r < 4; ++r) {
          const int s = bm + mi * 16 + g * 4 + r;
          dst[(size_t)s * D_DIM + col] = (float)acc[mi][jt][r] * scv;
        }
      }
    }
  }
}

// ---------------------------------------------------------------------------
// Flash attention: block = (q-tile of 64, head). 4 waves; wave w owns queries
// w*16..+15 (all 128 dims). QK^T: int8 MFMA (exact int32), K frags loaded
// straight from global (L1/L2-cached). Online softmax per q-row (4 rows/lane,
// cross-lane max/sum over the 16-lane group). P -> A-layout via per-wave LDS
// round-trip, split hi/lo bf16 (error ~2^-17). PV: bf16 MFMA, V frags direct
// from global vT[d][s] bf16.
// ---------------------------------------------------------------------------
__global__ __launch_bounds__(256) void attn_mfma(
    const int8_t* __restrict__ q8, const int8_t* __restrict__ k8,
    const unsigned short* __restrict__ vT, int8_t* __restrict__ o8) {
  const int qb = blockIdx.x;  // q-tile 0..31
  const int h = blockIdx.y;
  const int t = threadIdx.x;
  const int w = t >> 6, lane = t & 63, g = lane >> 4, l15 = lane & 15;
  __shared__ __align__(16) float Pl[4][16][76];  // per-wave P[q16][64keys]; pad 76: 2-way

  const int qrow = qb * 64 + w * 16 + l15;
  const v4i qa0 = *(const v4i*)(q8 + (size_t)qrow * D_DIM + h * HDIM + g * 16);
  const v4i qa1 = *(const v4i*)(q8 + (size_t)qrow * D_DIM + h * HDIM + 64 + g * 16);

  v4f o[8];
#pragma unroll
  for (int i = 0; i < 8; ++i) o[i] = (v4f){0.f, 0.f, 0.f, 0.f};
  float m_i[4] = {-INFINITY, -INFINITY, -INFINITY, -INFINITY};
  float l_i[4] = {0.f, 0.f, 0.f, 0.f};
  const float SSCALE = 8.838834764831845e-4f;  // 0.01 / sqrt(128)

  for (int kt = 0; kt <= qb; ++kt) {
    // ---- scores: int8 MFMA ----
    v4i s32[4];
#pragma unroll
    for (int nt = 0; nt < 4; ++nt) {
      const int key = kt * 64 + nt * 16 + l15;
      const v4i kb0 = *(const v4i*)(k8 + (size_t)key * D_DIM + h * HDIM + g * 16);
      const v4i kb1 = *(const v4i*)(k8 + (size_t)key * D_DIM + h * HDIM + 64 + g * 16);
      v4i c = (v4i){0, 0, 0, 0};
      c = __builtin_amdgcn_mfma_i32_16x16x64_i8(qa0, kb0, c, 0, 0, 0);
      c = __builtin_amdgcn_mfma_i32_16x16x64_i8(qa1, kb1, c, 0, 0, 0);
      s32[nt] = c;
    }
    float sc[4][4];
#pragma unroll
    for (int nt = 0; nt < 4; ++nt)
#pragma unroll
      for (int r = 0; r < 4; ++r) {
        float s = (float)s32[nt][r] * SSCALE;
        if (kt == qb) {  // diagonal tile: causal mask (exp -> 0, exact)
          const int key = kt * 64 + nt * 16 + l15;
          const int q = qb * 64 + w * 16 + g * 4 + r;
          if (key > q) s = -1.0e30f;
        }
        sc[nt][r] = s;
      }
    // ---- online softmax ----
    float alpha[4], rsum[4];
#pragma unroll
    for (int r = 0; r < 4; ++r) {
      float mx = fmaxf(fmaxf(sc[0][r], sc[1][r]), fmaxf(sc[2][r], sc[3][r]));
#pragma unroll
      for (int off = 1; off < 16; off <<= 1) mx = fmaxf(mx, __shfl_xor(mx, off));
      const float mnew = fmaxf(m_i[r], mx);
      alpha[r] = expf(m_i[r] - mnew);
      m_i[r] = mnew;
      rsum[r] = 0.f;
    }
#pragma unroll
    for (int nt = 0; nt < 4; ++nt)
#pragma unroll
      for (int r = 0; r < 4; ++r) {
        const float p = expf(sc[nt][r] - m_i[r]);
        rsum[r] += p;
        Pl[w][g * 4 + r][nt * 16 + l15] = p;
      }
#pragma unroll
    for (int r = 0; r < 4; ++r) {
#pragma unroll
      for (int off = 1; off < 16; off <<= 1) rsum[r] += __shfl_xor(rsum[r], off);
      l_i[r] = l_i[r] * alpha[r] + rsum[r];
    }
    // rescale O before accumulating this tile
#pragma unroll
    for (int nt = 0; nt < 8; ++nt)
#pragma unroll
      for (int r = 0; r < 4; ++r) o[nt][r] *= alpha[r];
    __syncthreads();  // order Pl writes before A-frag reads (also cross-iter)

    // ---- P -> hi/lo bf16 A-frags ----
    v8s ph[2], plo[2];
#pragma unroll
    for (int ks = 0; ks < 2; ++ks) {
      const float* pr = &Pl[w][l15][ks * 32 + g * 8];
      const v4f pa = *(const v4f*)pr;
      const v4f pb = *(const v4f*)(pr + 4);
      const float pf[8] = {pa.x, pa.y, pa.z, pa.w, pb.x, pb.y, pb.z, pb.w};
#pragma unroll
      for (int j = 0; j < 8; ++j) {
        const unsigned short hb = bf16_rne(pf[j]);
        ph[ks][j] = (short)hb;
        plo[ks][j] = (short)bf16_rne(pf[j] - bf16f(hb));
      }
    }
    // ---- PV: bf16 MFMA, V direct from global vT[d][s] ----
#pragma unroll
    for (int nt = 0; nt < 8; ++nt) {
      const unsigned short* vp =
          vT + (size_t)(h * HDIM + nt * 16 + l15) * S_LEN + kt * 64 + g * 8;
      const v8s v0 = *(const v8s*)vp;
      const v8s v1 = *(const v8s*)(vp + 32);
      o[nt] = __builtin_amdgcn_mfma_f32_16x16x32_bf16(ph[0], v0, o[nt], 0, 0, 0);
      o[nt] = __builtin_amdgcn_mfma_f32_16x16x32_bf16(plo[0], v0, o[nt], 0, 0, 0);
      o[nt] = __builtin_amdgcn_mfma_f32_16x16x32_bf16(ph[1], v1, o[nt], 0, 0, 0);
      o[nt] = __builtin_amdgcn_mfma_f32_16x16x32_bf16(plo[1], v1, o[nt], 0, 0, 0);
    }
    __syncthreads();  // protect Pl against next-iteration overwrite
  }

  // ---- epilogue: normalize, *0.1 (V scale), fake-quant ±127 ----
#pragma unroll
  for (int nt = 0; nt < 8; ++nt)
#pragma unroll
    for (int r = 0; r < 4; ++r) {
      const float val = o[nt][r] * 0.1f / l_i[r];
      const float q = fminf(fmaxf(rintf(val / 0.1f), -127.f), 127.f);
      o8[(size_t)(qb * 64 + w * 16 + g * 4 + r) * D_DIM + h * HDIM + nt * 16 + l15] =
          (int8_t)q;
    }
}

// ---------------------------------------------------------------------------
extern "C" void kernel_launch(void* const* d_in, const int* in_sizes, int n_in,
                              void* d_out, int out_size, void* d_ws, size_t ws_size,
                              hipStream_t stream) {
  (void)in_sizes; (void)n_in; (void)out_size; (void)ws_size;
  const float* hidden = (const float*)d_in[0];
  const float* wq = (const float*)d_in[1];
  const float* wk = (const float*)d_in[2];
  const float* wv = (const float*)d_in[3];
  const float* wo = (const float*)d_in[4];
  const float* sq = (const float*)d_in[5];
  const float* sk = (const float*)d_in[6];
  const float* sv = (const float*)d_in[7];
  const float* so = (const float*)d_in[8];
  // d_in[9] = attention_mask (pure causal; handled analytically)
  const int* pos = (const int*)d_in[10];
  float* out = (float*)d_out;

  char* ws = (char*)d_ws;
  int8_t* h8 = (int8_t*)ws;                                  // 8 MB (later o8)
  int8_t* q8 = (int8_t*)(ws + (8ull << 20));                 // 8 MB
  int8_t* k8 = (int8_t*)(ws + (16ull << 20));                // 8 MB
  unsigned short* vT = (unsigned short*)(ws + (24ull << 20)); // 16 MB bf16 [D][S]
  int8_t* w8a = (int8_t*)(ws + (40ull << 20));               // 16 MB (wq, later wo)
  int8_t* w8b = (int8_t*)(ws + (56ull << 20));               // 16 MB (wk)
  int8_t* w8c = (int8_t*)(ws + (72ull << 20));               // 16 MB (wv)
  float* ctab = (float*)(ws + (88ull << 20));                // 512 KB
  float* stab = (float*)(ws + (88ull << 20) + (512ull << 10));
  int8_t* o8 = h8;  // h8 dead after v-GEMM; attn writes o8 there

  hipLaunchKernelGGL(rope_tab_k, dim3(512), dim3(256), 0, stream, pos, ctab, stab);
  hipLaunchKernelGGL(quant_hidden_k, dim3(8192), dim3(256), 0, stream, hidden, h8);
  hipLaunchKernelGGL(wconv_k, dim3(16384), dim3(256), 0, stream, wq, w8a);
  hipLaunchKernelGGL(wconv_k, dim3(16384), dim3(256), 0, stream, wk, w8b);
  hipLaunchKernelGGL(wconv_k, dim3(16384), dim3(256), 0, stream, wv, w8c);

  const dim3 gg(32, 16), gb(256);
  hipLaunchKernelGGL((gemm_i8<0>), gg, gb, 0, stream, h8, w8a, sq, ctab, stab, (void*)q8);
  hipLaunchKernelGGL((gemm_i8<1>), gg, gb, 0, stream, h8, w8b, sk, ctab, stab, (void*)k8);
  hipLaunchKernelGGL((gemm_i8<2>), gg, gb, 0, stream, h8, w8c, sv, ctab, stab, (void*)vT);
  hipLaunchKernelGGL(wconv_k, dim3(16384), dim3(256), 0, stream, wo, w8a);  // wq dead
  hipLaunchKernelGGL(attn_mfma, dim3(32, 32), dim3(256), 0, stream, q8, k8, vT, o8);
  hipLaunchKernelGGL((gemm_i8<3>), gg, gb, 0, stream, o8, w8a, so, ctab, stab, (void*)out);
}

// Round 3
// 776.306 us; speedup vs baseline: 13.1907x; 1.2097x over previous
//
#include <hip/hip_runtime.h>
#include <math.h>
#include <stdint.h>

#define S_LEN 2048
#define D_DIM 4096
#define NHEAD 32
#define HDIM  128

typedef int   v4i __attribute__((ext_vector_type(4)));
typedef float v4f __attribute__((ext_vector_type(4)));
typedef short v8s __attribute__((ext_vector_type(8)));

__device__ __forceinline__ float quant128(float x) {
  return fminf(fmaxf(rintf(x / 0.1f), -128.f), 127.f);
}
__device__ __forceinline__ unsigned short bf16_rne(float f) {
  unsigned u = __float_as_uint(f);
  unsigned r = u + 0x7fffu + ((u >> 16) & 1u);
  return (unsigned short)(r >> 16);
}
__device__ __forceinline__ float bf16f(unsigned short h) {
  return __uint_as_float(((unsigned)h) << 16);
}

// ---------------- prep kernels ----------------
__global__ __launch_bounds__(256) void quant_hidden_k(const float* __restrict__ in,
                                                      int8_t* __restrict__ out) {
  const int idx = blockIdx.x * 256 + threadIdx.x;
  const float4 v = ((const float4*)in)[idx];
  const int q0 = (int)quant128(v.x), q1 = (int)quant128(v.y);
  const int q2 = (int)quant128(v.z), q3 = (int)quant128(v.w);
  ((int*)out)[idx] = (q0 & 0xff) | ((q1 & 0xff) << 8) | ((q2 & 0xff) << 16) | ((q3 & 0xff) << 24);
}

__global__ __launch_bounds__(256) void wconv_k(const float* __restrict__ in,
                                               int8_t* __restrict__ out) {
  const int idx = blockIdx.x * 256 + threadIdx.x;
  const float4 v = ((const float4*)in)[idx];  // int4-valued floats (-8..7), exact
  const int q0 = __float2int_rn(v.x), q1 = __float2int_rn(v.y);
  const int q2 = __float2int_rn(v.z), q3 = __float2int_rn(v.w);
  ((int*)out)[idx] = (q0 & 0xff) | ((q1 & 0xff) << 8) | ((q2 & 0xff) << 16) | ((q3 & 0xff) << 24);
}

__global__ __launch_bounds__(256) void rope_tab_k(const int* __restrict__ pos,
                                                  float* __restrict__ ct,
                                                  float* __restrict__ st) {
  const int idx = blockIdx.x * 256 + threadIdx.x;  // [S][64]
  const int s = idx >> 6, j = idx & 63;
  const float inv = exp2f((float)j * -0.20762050593046016f);  // 10000^(-j/64)
  const float a = (float)pos[s] * inv;
  float si, c;
  sincosf(a, &si, &c);
  ct[idx] = c;
  st[idx] = si;
}

// ---------------------------------------------------------------------------
// int8 MFMA GEMM (unchanged from round 2): C[s,o] = (sum_d A8*W8) * (0.1*wsc[o])
// ---------------------------------------------------------------------------
template <int OMODE>
__global__ __launch_bounds__(256) void gemm_i8(
    const int8_t* __restrict__ A8, const int8_t* __restrict__ W8,
    const float* __restrict__ wsc, const float* __restrict__ ctab,
    const float* __restrict__ stab, void* __restrict__ outp) {
  __shared__ __align__(16) int8_t Als[128 * 80];
  __shared__ __align__(16) int8_t Bls[128 * 80];
  const int t = threadIdx.x;
  const int w = t >> 6, lane = t & 63, g = lane >> 4, l15 = lane & 15;
  const int bm = blockIdx.y * 128, bn = blockIdx.x * 128;
  const int srow = t >> 1, soff = (t & 1) * 32;

  v4i acc[8][2];
#pragma unroll
  for (int i = 0; i < 8; ++i) {
    acc[i][0] = (v4i){0, 0, 0, 0};
    acc[i][1] = (v4i){0, 0, 0, 0};
  }

  const int8_t* Aptr = A8 + (size_t)(bm + srow) * D_DIM + soff;
  const int8_t* Bptr = W8 + (size_t)(bn + srow) * D_DIM + soff;
  int8_t* Alw = Als + srow * 80 + soff;
  int8_t* Blw = Bls + srow * 80 + soff;

  for (int k0 = 0; k0 < D_DIM; k0 += 64) {
    const int4 a0 = *(const int4*)(Aptr + k0);
    const int4 a1 = *(const int4*)(Aptr + k0 + 16);
    const int4 b0 = *(const int4*)(Bptr + k0);
    const int4 b1 = *(const int4*)(Bptr + k0 + 16);
    *(int4*)(Alw) = a0;
    *(int4*)(Alw + 16) = a1;
    *(int4*)(Blw) = b0;
    *(int4*)(Blw + 16) = b1;
    __syncthreads();
    const v4i bf0 = *(const v4i*)(Bls + (w * 16 + l15) * 80 + g * 16);
    const v4i bf1 = *(const v4i*)(Bls + (w * 16 + 64 + l15) * 80 + g * 16);
#pragma unroll
    for (int mi = 0; mi < 8; ++mi) {
      const v4i af = *(const v4i*)(Als + (mi * 16 + l15) * 80 + g * 16);
      acc[mi][0] = __builtin_amdgcn_mfma_i32_16x16x64_i8(af, bf0, acc[mi][0], 0, 0, 0);
      acc[mi][1] = __builtin_amdgcn_mfma_i32_16x16x64_i8(af, bf1, acc[mi][1], 0, 0, 0);
    }
    __syncthreads();
  }

  if (OMODE == 0 || OMODE == 1) {
    const int jcol = w * 16 + l15;  // 0..63
    const float sc0 = 0.1f * wsc[bn + jcol];
    const float sc1 = 0.1f * wsc[bn + jcol + 64];
    int8_t* dst = (int8_t*)outp;
#pragma unroll
    for (int mi = 0; mi < 8; ++mi) {
#pragma unroll
      for (int r = 0; r < 4; ++r) {
        const int s = bm + mi * 16 + g * 4 + r;
        const float c = ctab[s * 64 + jcol];
        const float si = stab[s * 64 + jcol];
        const float x1 = (float)acc[mi][0][r] * sc0;
        const float x2 = (float)acc[mi][1][r] * sc1;
        dst[(size_t)s * D_DIM + bn + jcol] = (int8_t)quant128(x1 * c - x2 * si);
        dst[(size_t)s * D_DIM + bn + jcol + 64] = (int8_t)quant128(x2 * c + x1 * si);
      }
    }
  } else if (OMODE == 2) {
    unsigned short* dst = (unsigned short*)outp;
#pragma unroll
    for (int jt = 0; jt < 2; ++jt) {
      const int col = bn + w * 16 + jt * 64 + l15;
      const float scv = 0.1f * wsc[col];
#pragma unroll
      for (int mi = 0; mi < 8; ++mi) {
#pragma unroll
        for (int r = 0; r < 4; ++r) {
          const int s = bm + mi * 16 + g * 4 + r;
          const float q = quant128((float)acc[mi][jt][r] * scv);
          dst[(size_t)col * S_LEN + s] = (unsigned short)(__float_as_uint(q) >> 16);
        }
      }
    }
  } else {
    float* dst = (float*)outp;
#pragma unroll
    for (int jt = 0; jt < 2; ++jt) {
      const int col = bn + w * 16 + jt * 64 + l15;
      const float scv = 0.1f * wsc[col];
#pragma unroll
      for (int mi = 0; mi < 8; ++mi) {
#pragma unroll
        for (int r = 0; r < 4; ++r) {
          const int s = bm + mi * 16 + g * 4 + r;
          dst[(size_t)s * D_DIM + col] = (float)acc[mi][jt][r] * scv;
        }
      }
    }
  }
}

// ---------------------------------------------------------------------------
// Flash attention v2: block = (16 query rows, head); grid (128, 32).
// The 4 waves SPLIT THE KEY TILES (wave w: kt = w, w+4, ...) — per-wave chain
// <= 8 tiles, no duplicated K/V loads, and ZERO barriers in the K loop (the
// P-staging LDS is per-wave; intra-wave ds ordering is enough). Each wave
// keeps its own online-softmax state (m,l,O); partials are merged at the end
// via exp(m_w - M) rescale in LDS (2 barriers total).
// ---------------------------------------------------------------------------
__global__ __launch_bounds__(256) void attn_mfma(
    const int8_t* __restrict__ q8, const int8_t* __restrict__ k8,
    const unsigned short* __restrict__ vT, int8_t* __restrict__ o8) {
  const int qt = (int)gridDim.x - 1 - (int)blockIdx.x;  // heavy tiles first
  const int h = blockIdx.y;
  const int t = threadIdx.x;
  const int w = t >> 6, lane = t & 63, g = lane >> 4, l15 = lane & 15;
  const int q0 = qt * 16;
  const int T = (q0 + 15) / 64 + 1;  // number of 64-key tiles

  // union: Pst[4][16][76] (loop) / Ol[4][16][132] (merge); Ml/Ll beyond both.
  __shared__ __align__(16) float smem[4 * 16 * 132 + 128];
  float* Pw = smem + w * 16 * 76;          // this wave's P staging
  float* Ml = smem + 4 * 16 * 132;         // [w*16 + row]
  float* Ll = Ml + 64;

  const v4i qa0 = *(const v4i*)(q8 + (size_t)(q0 + l15) * D_DIM + h * HDIM + g * 16);
  const v4i qa1 = *(const v4i*)(q8 + (size_t)(q0 + l15) * D_DIM + h * HDIM + 64 + g * 16);

  v4f o[8];
#pragma unroll
  for (int i = 0; i < 8; ++i) o[i] = (v4f){0.f, 0.f, 0.f, 0.f};
  float m_i[4] = {-INFINITY, -INFINITY, -INFINITY, -INFINITY};
  float l_i[4] = {0.f, 0.f, 0.f, 0.f};
  const float SSCALE = 8.838834764831845e-4f;  // 0.01 / sqrt(128)

  for (int kt = w; kt < T; kt += 4) {
    // ---- scores: int8 MFMA (exact int32) ----
    v4i s32[4];
#pragma unroll
    for (int nt = 0; nt < 4; ++nt) {
      const int key = kt * 64 + nt * 16 + l15;
      const v4i kb0 = *(const v4i*)(k8 + (size_t)key * D_DIM + h * HDIM + g * 16);
      const v4i kb1 = *(const v4i*)(k8 + (size_t)key * D_DIM + h * HDIM + 64 + g * 16);
      v4i c = (v4i){0, 0, 0, 0};
      c = __builtin_amdgcn_mfma_i32_16x16x64_i8(qa0, kb0, c, 0, 0, 0);
      c = __builtin_amdgcn_mfma_i32_16x16x64_i8(qa1, kb1, c, 0, 0, 0);
      s32[nt] = c;
    }
    float sc[4][4];
#pragma unroll
    for (int nt = 0; nt < 4; ++nt)
#pragma unroll
      for (int r = 0; r < 4; ++r) {
        float s = (float)s32[nt][r] * SSCALE;
        if (kt == T - 1) {  // only the last tile can cross the diagonal
          const int key = kt * 64 + nt * 16 + l15;
          const int q = q0 + g * 4 + r;
          if (key > q) s = -1.0e30f;
        }
        sc[nt][r] = s;
      }
    // ---- online softmax (per wave) ----
    float alpha[4], rsum[4];
#pragma unroll
    for (int r = 0; r < 4; ++r) {
      float mx = fmaxf(fmaxf(sc[0][r], sc[1][r]), fmaxf(sc[2][r], sc[3][r]));
#pragma unroll
      for (int off = 1; off < 16; off <<= 1) mx = fmaxf(mx, __shfl_xor(mx, off));
      const float mnew = fmaxf(m_i[r], mx);
      alpha[r] = __expf(m_i[r] - mnew);
      m_i[r] = mnew;
      rsum[r] = 0.f;
    }
#pragma unroll
    for (int nt = 0; nt < 4; ++nt)
#pragma unroll
      for (int r = 0; r < 4; ++r) {
        const float p = __expf(sc[nt][r] - m_i[r]);
        rsum[r] += p;
        Pw[(g * 4 + r) * 76 + nt * 16 + l15] = p;
      }
#pragma unroll
    for (int r = 0; r < 4; ++r) {
#pragma unroll
      for (int off = 1; off < 16; off <<= 1) rsum[r] += __shfl_xor(rsum[r], off);
      l_i[r] = l_i[r] * alpha[r] + rsum[r];
    }
#pragma unroll
    for (int nt = 0; nt < 8; ++nt)
#pragma unroll
      for (int r = 0; r < 4; ++r) o[nt][r] *= alpha[r];

    // ---- P -> hi/lo bf16 A-frags (per-wave LDS round-trip, NO barrier) ----
    v8s ph[2], plo[2];
#pragma unroll
    for (int ks = 0; ks < 2; ++ks) {
      const float* pr = &Pw[l15 * 76 + ks * 32 + g * 8];
      const v4f pa = *(const v4f*)pr;
      const v4f pb = *(const v4f*)(pr + 4);
      const float pf[8] = {pa.x, pa.y, pa.z, pa.w, pb.x, pb.y, pb.z, pb.w};
#pragma unroll
      for (int j = 0; j < 8; ++j) {
        const unsigned short hb = bf16_rne(pf[j]);
        ph[ks][j] = (short)hb;
        plo[ks][j] = (short)bf16_rne(pf[j] - bf16f(hb));
      }
    }
    // ---- PV: bf16 MFMA, V direct from global vT[d][s] ----
#pragma unroll
    for (int nt = 0; nt < 8; ++nt) {
      const unsigned short* vp =
          vT + (size_t)(h * HDIM + nt * 16 + l15) * S_LEN + kt * 64 + g * 8;
      const v8s v0 = *(const v8s*)vp;
      const v8s v1 = *(const v8s*)(vp + 32);
      o[nt] = __builtin_amdgcn_mfma_f32_16x16x32_bf16(ph[0], v0, o[nt], 0, 0, 0);
      o[nt] = __builtin_amdgcn_mfma_f32_16x16x32_bf16(plo[0], v0, o[nt], 0, 0, 0);
      o[nt] = __builtin_amdgcn_mfma_f32_16x16x32_bf16(ph[1], v1, o[nt], 0, 0, 0);
      o[nt] = __builtin_amdgcn_mfma_f32_16x16x32_bf16(plo[1], v1, o[nt], 0, 0, 0);
    }
  }

  // ---- merge the 4 waves' (m, l, O) ----
  if (l15 == 0) {
#pragma unroll
    for (int r = 0; r < 4; ++r) {
      Ml[w * 16 + g * 4 + r] = m_i[r];
      Ll[w * 16 + g * 4 + r] = l_i[r];
    }
  }
  __syncthreads();  // (m,l) visible; all waves done with their Pst region
  float scale[4];
#pragma unroll
  for (int r = 0; r < 4; ++r) {
    const int row = g * 4 + r;
    float M = Ml[row];
    M = fmaxf(M, Ml[16 + row]);
    M = fmaxf(M, Ml[32 + row]);
    M = fmaxf(M, Ml[48 + row]);
    scale[r] = __expf(m_i[r] - M);  // 0 for idle waves (m=-inf)
  }
  float* Ol = smem;  // [w][16][132], aliases Pst (dead now)
#pragma unroll
  for (int nt = 0; nt < 8; ++nt)
#pragma unroll
    for (int r = 0; r < 4; ++r)
      Ol[(w * 16 + g * 4 + r) * 132 + nt * 16 + l15] = o[nt][r] * scale[r];
  __syncthreads();

  // final: each thread -> 8 consecutive d of one row
  const int row = t >> 4, dbase = (t & 15) * 8;
  float M = Ml[row];
  M = fmaxf(M, Ml[16 + row]);
  M = fmaxf(M, Ml[32 + row]);
  M = fmaxf(M, Ml[48 + row]);
  float L = 0.f;
#pragma unroll
  for (int ww = 0; ww < 4; ++ww) L += __expf(Ml[ww * 16 + row] - M) * Ll[ww * 16 + row];
  unsigned lo = 0, hi = 0;
#pragma unroll
  for (int j = 0; j < 8; ++j) {
    float res = 0.f;
#pragma unroll
    for (int ww = 0; ww < 4; ++ww) res += Ol[(ww * 16 + row) * 132 + dbase + j];
    // out = res*0.1/L, out_q = rint(out/0.1) clamp ±127  (0.1 cancels exactly)
    const int q = (int)fminf(fmaxf(rintf(res / L), -127.f), 127.f) & 0xff;
    if (j < 4) lo |= (unsigned)q << (8 * j);
    else       hi |= (unsigned)q << (8 * (j - 4));
  }
  *(int2*)(o8 + (size_t)(q0 + row) * D_DIM + h * HDIM + dbase) = make_int2((int)lo, (int)hi);
}

// ---------------------------------------------------------------------------
extern "C" void kernel_launch(void* const* d_in, const int* in_sizes, int n_in,
                              void* d_out, int out_size, void* d_ws, size_t ws_size,
                              hipStream_t stream) {
  (void)in_sizes; (void)n_in; (void)out_size; (void)ws_size;
  const float* hidden = (const float*)d_in[0];
  const float* wq = (const float*)d_in[1];
  const float* wk = (const float*)d_in[2];
  const float* wv = (const float*)d_in[3];
  const float* wo = (const float*)d_in[4];
  const float* sq = (const float*)d_in[5];
  const float* sk = (const float*)d_in[6];
  const float* sv = (const float*)d_in[7];
  const float* so = (const float*)d_in[8];
  // d_in[9] = attention_mask (pure causal; handled analytically)
  const int* pos = (const int*)d_in[10];
  float* out = (float*)d_out;

  char* ws = (char*)d_ws;
  int8_t* h8 = (int8_t*)ws;                                   // 8 MB (later o8)
  int8_t* q8 = (int8_t*)(ws + (8ull << 20));                  // 8 MB
  int8_t* k8 = (int8_t*)(ws + (16ull << 20));                 // 8 MB
  unsigned short* vT = (unsigned short*)(ws + (24ull << 20)); // 16 MB bf16 [D][S]
  int8_t* w8a = (int8_t*)(ws + (40ull << 20));                // 16 MB (wq, later wo)
  int8_t* w8b = (int8_t*)(ws + (56ull << 20));                // 16 MB (wk)
  int8_t* w8c = (int8_t*)(ws + (72ull << 20));                // 16 MB (wv)
  float* ctab = (float*)(ws + (88ull << 20));                 // 512 KB
  float* stab = (float*)(ws + (88ull << 20) + (512ull << 10));
  int8_t* o8 = h8;  // h8 dead after v-GEMM; attn writes o8 there

  hipLaunchKernelGGL(rope_tab_k, dim3(512), dim3(256), 0, stream, pos, ctab, stab);
  hipLaunchKernelGGL(quant_hidden_k, dim3(8192), dim3(256), 0, stream, hidden, h8);
  hipLaunchKernelGGL(wconv_k, dim3(16384), dim3(256), 0, stream, wq, w8a);
  hipLaunchKernelGGL(wconv_k, dim3(16384), dim3(256), 0, stream, wk, w8b);
  hipLaunchKernelGGL(wconv_k, dim3(16384), dim3(256), 0, stream, wv, w8c);

  const dim3 gg(32, 16), gb(256);
  hipLaunchKernelGGL((gemm_i8<0>), gg, gb, 0, stream, h8, w8a, sq, ctab, stab, (void*)q8);
  hipLaunchKernelGGL((gemm_i8<1>), gg, gb, 0, stream, h8, w8b, sk, ctab, stab, (void*)k8);
  hipLaunchKernelGGL((gemm_i8<2>), gg, gb, 0, stream, h8, w8c, sv, ctab, stab, (void*)vT);
  hipLaunchKernelGGL(wconv_k, dim3(16384), dim3(256), 0, stream, wo, w8a);  // wq dead
  hipLaunchKernelGGL(attn_mfma, dim3(128, 32), dim3(256), 0, stream, q8, k8, vT, o8);
  hipLaunchKernelGGL((gemm_i8<3>), gg, gb, 0, stream, o8, w8a, so, ctab, stab, (void*)out);
}

// Round 4
// 681.431 us; speedup vs baseline: 15.0272x; 1.1392x over previous
//
#include <hip/hip_runtime.h>
#include <math.h>
#include <stdint.h>

#define S_LEN 2048
#define D_DIM 4096
#define NHEAD 32
#define HDIM  128

typedef int   v4i __attribute__((ext_vector_type(4)));
typedef float v4f __attribute__((ext_vector_type(4)));
typedef short v8s __attribute__((ext_vector_type(8)));

__device__ __forceinline__ float quant128(float x) {
  return fminf(fmaxf(rintf(x / 0.1f), -128.f), 127.f);
}
__device__ __forceinline__ unsigned short bf16_rne(float f) {
  unsigned u = __float_as_uint(f);
  unsigned r = u + 0x7fffu + ((u >> 16) & 1u);
  return (unsigned short)(r >> 16);
}
__device__ __forceinline__ float bf16f(unsigned short h) {
  return __uint_as_float(((unsigned)h) << 16);
}
// async 16B global->LDS DMA; LDS side is wave-uniform base + lane*16
__device__ __forceinline__ void gl_lds16(const void* g, void* l) {
  __builtin_amdgcn_global_load_lds(
      (const __attribute__((address_space(1))) void*)g,
      (__attribute__((address_space(3))) void*)l, 16, 0, 0);
}

// ---------------- prep kernels ----------------
__global__ __launch_bounds__(256) void quant_hidden_k(const float* __restrict__ in,
                                                      int8_t* __restrict__ out) {
  const int idx = blockIdx.x * 256 + threadIdx.x;
  const float4 v = ((const float4*)in)[idx];
  const int q0 = (int)quant128(v.x), q1 = (int)quant128(v.y);
  const int q2 = (int)quant128(v.z), q3 = (int)quant128(v.w);
  ((int*)out)[idx] = (q0 & 0xff) | ((q1 & 0xff) << 8) | ((q2 & 0xff) << 16) | ((q3 & 0xff) << 24);
}

// fused f32->int8 convert of wq,wk,wv into one contiguous 48MB dst
__global__ __launch_bounds__(256) void wconv3_k(const float* __restrict__ a,
                                                const float* __restrict__ b,
                                                const float* __restrict__ c,
                                                int8_t* __restrict__ out) {
  const int which = blockIdx.x >> 14;  // 16384 blocks per 16M-element source
  const int sub = blockIdx.x & 16383;
  const float* src = (which == 0) ? a : (which == 1) ? b : c;
  const int idx = sub * 256 + threadIdx.x;
  const float4 v = ((const float4*)src)[idx];  // int4-valued floats, exact
  const int q0 = __float2int_rn(v.x), q1 = __float2int_rn(v.y);
  const int q2 = __float2int_rn(v.z), q3 = __float2int_rn(v.w);
  ((int*)out)[(size_t)which * 4194304 + idx] =
      (q0 & 0xff) | ((q1 & 0xff) << 8) | ((q2 & 0xff) << 16) | ((q3 & 0xff) << 24);
}

__global__ __launch_bounds__(256) void wconv_k(const float* __restrict__ in,
                                               int8_t* __restrict__ out) {
  const int idx = blockIdx.x * 256 + threadIdx.x;
  const float4 v = ((const float4*)in)[idx];
  const int q0 = __float2int_rn(v.x), q1 = __float2int_rn(v.y);
  const int q2 = __float2int_rn(v.z), q3 = __float2int_rn(v.w);
  ((int*)out)[idx] = (q0 & 0xff) | ((q1 & 0xff) << 8) | ((q2 & 0xff) << 16) | ((q3 & 0xff) << 24);
}

__global__ __launch_bounds__(256) void rope_tab_k(const int* __restrict__ pos,
                                                  float* __restrict__ ct,
                                                  float* __restrict__ st) {
  const int idx = blockIdx.x * 256 + threadIdx.x;  // [S][64]
  const int s = idx >> 6, j = idx & 63;
  const float inv = exp2f((float)j * -0.20762050593046016f);  // 10000^(-j/64)
  const float a = (float)pos[s] * inv;
  float si, c;
  sincosf(a, &si, &c);
  ct[idx] = c;
  st[idx] = si;
}

// ---------------------------------------------------------------------------
// int8 MFMA GEMM v2: staging via global_load_lds (16B DMA, no VGPR round-trip).
// LDS tile 128 rows x 64B, XOR-swizzled: LDS chunk (m,c) holds global chunk
// c ^ ((m>>1)&3), so DMA's lane-contiguous write gives a layout whose
// fragment reads hit 8 banks x 2 lanes per 16-lane group (2-way = free, m136).
// ---------------------------------------------------------------------------
template <int OMODE>
__global__ __launch_bounds__(256) void gemm_i8(
    const int8_t* __restrict__ A8, const int8_t* __restrict__ W8,
    const float* __restrict__ wsc, const float* __restrict__ ctab,
    const float* __restrict__ stab, void* __restrict__ outp) {
  __shared__ __align__(16) int8_t Als[8192];
  __shared__ __align__(16) int8_t Bls[8192];
  const int t = threadIdx.x;
  const int w = t >> 6, lane = t & 63, g = lane >> 4, l15 = lane & 15;
  const int bm = blockIdx.y * 128, bn = blockIdx.x * 128;

  // staging: wave w DMAs segments {2w, 2w+1} (16 rows x 64B each) of A and B.
  const int mrow0 = (w * 2) * 16 + (lane >> 2);
  const int mrow1 = mrow0 + 16;
  const int gph = ((lane & 3) ^ ((lane >> 3) & 3)) * 16;  // source chunk swizzle
  const int8_t* srcA0 = A8 + (size_t)(bm + mrow0) * D_DIM + gph;
  const int8_t* srcA1 = A8 + (size_t)(bm + mrow1) * D_DIM + gph;
  const int8_t* srcB0 = W8 + (size_t)(bn + mrow0) * D_DIM + gph;
  const int8_t* srcB1 = W8 + (size_t)(bn + mrow1) * D_DIM + gph;
  int8_t* dA0 = Als + (w * 2) * 1024;
  int8_t* dA1 = dA0 + 1024;
  int8_t* dB0 = Bls + (w * 2) * 1024;
  int8_t* dB1 = dB0 + 1024;

  // fragment LDS offsets (loop-invariant): row r chunk g at r*64+(g^((r>>1)&3))*16
  const int chunk = ((g ^ ((l15 >> 1) & 3)) * 16) + l15 * 64;
  const int boff0 = w * 1024 + chunk;
  const int boff1 = boff0 + 4096;

  v4i acc[8][2];
#pragma unroll
  for (int i = 0; i < 8; ++i) {
    acc[i][0] = (v4i){0, 0, 0, 0};
    acc[i][1] = (v4i){0, 0, 0, 0};
  }

  for (int k0 = 0; k0 < D_DIM; k0 += 64) {
    gl_lds16(srcA0 + k0, dA0);
    gl_lds16(srcA1 + k0, dA1);
    gl_lds16(srcB0 + k0, dB0);
    gl_lds16(srcB1 + k0, dB1);
    __syncthreads();  // drains vmcnt (DMA) before fragment reads
    const v4i bf0 = *(const v4i*)(Bls + boff0);
    const v4i bf1 = *(const v4i*)(Bls + boff1);
#pragma unroll
    for (int mi = 0; mi < 8; ++mi) {
      const v4i af = *(const v4i*)(Als + mi * 1024 + chunk);
      acc[mi][0] = __builtin_amdgcn_mfma_i32_16x16x64_i8(af, bf0, acc[mi][0], 0, 0, 0);
      acc[mi][1] = __builtin_amdgcn_mfma_i32_16x16x64_i8(af, bf1, acc[mi][1], 0, 0, 0);
    }
    __syncthreads();  // reads done before next DMA overwrites
  }

  if (OMODE == 0 || OMODE == 1) {
    const int jcol = w * 16 + l15;  // 0..63
    const float sc0 = 0.1f * wsc[bn + jcol];
    const float sc1 = 0.1f * wsc[bn + jcol + 64];
    int8_t* dst = (int8_t*)outp;
#pragma unroll
    for (int mi = 0; mi < 8; ++mi) {
#pragma unroll
      for (int r = 0; r < 4; ++r) {
        const int s = bm + mi * 16 + g * 4 + r;
        const float c = ctab[s * 64 + jcol];
        const float si = stab[s * 64 + jcol];
        const float x1 = (float)acc[mi][0][r] * sc0;
        const float x2 = (float)acc[mi][1][r] * sc1;
        dst[(size_t)s * D_DIM + bn + jcol] = (int8_t)quant128(x1 * c - x2 * si);
        dst[(size_t)s * D_DIM + bn + jcol + 64] = (int8_t)quant128(x2 * c + x1 * si);
      }
    }
  } else if (OMODE == 2) {
    unsigned short* dst = (unsigned short*)outp;
#pragma unroll
    for (int jt = 0; jt < 2; ++jt) {
      const int col = bn + w * 16 + jt * 64 + l15;
      const float scv = 0.1f * wsc[col];
#pragma unroll
      for (int mi = 0; mi < 8; ++mi) {
#pragma unroll
        for (int r = 0; r < 4; ++r) {
          const int s = bm + mi * 16 + g * 4 + r;
          const float q = quant128((float)acc[mi][jt][r] * scv);
          dst[(size_t)col * S_LEN + s] = (unsigned short)(__float_as_uint(q) >> 16);
        }
      }
    }
  } else {
    float* dst = (float*)outp;
#pragma unroll
    for (int jt = 0; jt < 2; ++jt) {
      const int col = bn + w * 16 + jt * 64 + l15;
      const float scv = 0.1f * wsc[col];
#pragma unroll
      for (int mi = 0; mi < 8; ++mi) {
#pragma unroll
        for (int r = 0; r < 4; ++r) {
          const int s = bm + mi * 16 + g * 4 + r;
          dst[(size_t)s * D_DIM + col] = (float)acc[mi][jt][r] * scv;
        }
      }
    }
  }
}

// ---------------------------------------------------------------------------
// Flash attention v3: persistent-ish uniform blocks. Grid (32,32) = 1024
// blocks (exactly 4/CU). Block (i,h) processes qt in {127-i, 64+i, 63-i, i}:
// total key-tiles = 66 for EVERY i (T(qt)=qt/4+1 telescopes), so all blocks
// finish together — no causal tail. Within an item the 4 waves split key
// tiles (barrier-free K loop, per-wave online softmax), merged in LDS.
// ---------------------------------------------------------------------------
__global__ __launch_bounds__(256) void attn_mfma(
    const int8_t* __restrict__ q8, const int8_t* __restrict__ k8,
    const unsigned short* __restrict__ vT, int8_t* __restrict__ o8) {
  const int i = blockIdx.x;
  const int h = blockIdx.y;
  const int t = threadIdx.x;
  const int w = t >> 6, lane = t & 63, g = lane >> 4, l15 = lane & 15;

  // union: Pst[4][16][76] (loop) / Ol[4][16][132] (merge); Ml/Ll beyond both.
  __shared__ __align__(16) float smem[4 * 16 * 132 + 128];
  float* Pw = smem + w * 16 * 76;
  float* Ml = smem + 4 * 16 * 132;
  float* Ll = Ml + 64;
  const float SSCALE = 8.838834764831845e-4f;  // 0.01 / sqrt(128)

  const int qlist[4] = {127 - i, 64 + i, 63 - i, i};

  for (int it = 0; it < 4; ++it) {
    const int qt = qlist[it];
    const int q0 = qt * 16;
    const int T = (qt >> 2) + 1;  // number of 64-key tiles

    const v4i qa0 = *(const v4i*)(q8 + (size_t)(q0 + l15) * D_DIM + h * HDIM + g * 16);
    const v4i qa1 = *(const v4i*)(q8 + (size_t)(q0 + l15) * D_DIM + h * HDIM + 64 + g * 16);

    v4f o[8];
#pragma unroll
    for (int n = 0; n < 8; ++n) o[n] = (v4f){0.f, 0.f, 0.f, 0.f};
    float m_i[4] = {-INFINITY, -INFINITY, -INFINITY, -INFINITY};
    float l_i[4] = {0.f, 0.f, 0.f, 0.f};

    for (int kt = w; kt < T; kt += 4) {
      // ---- scores: int8 MFMA (exact int32) ----
      v4i s32[4];
#pragma unroll
      for (int nt = 0; nt < 4; ++nt) {
        const int key = kt * 64 + nt * 16 + l15;
        const v4i kb0 = *(const v4i*)(k8 + (size_t)key * D_DIM + h * HDIM + g * 16);
        const v4i kb1 = *(const v4i*)(k8 + (size_t)key * D_DIM + h * HDIM + 64 + g * 16);
        v4i c = (v4i){0, 0, 0, 0};
        c = __builtin_amdgcn_mfma_i32_16x16x64_i8(qa0, kb0, c, 0, 0, 0);
        c = __builtin_amdgcn_mfma_i32_16x16x64_i8(qa1, kb1, c, 0, 0, 0);
        s32[nt] = c;
      }
      float sc[4][4];
#pragma unroll
      for (int nt = 0; nt < 4; ++nt)
#pragma unroll
        for (int r = 0; r < 4; ++r) {
          float s = (float)s32[nt][r] * SSCALE;
          if (kt == T - 1) {  // only the last tile can cross the diagonal
            const int key = kt * 64 + nt * 16 + l15;
            const int q = q0 + g * 4 + r;
            if (key > q) s = -1.0e30f;
          }
          sc[nt][r] = s;
        }
      // ---- online softmax (per wave) ----
      float alpha[4], rsum[4];
#pragma unroll
      for (int r = 0; r < 4; ++r) {
        float mx = fmaxf(fmaxf(sc[0][r], sc[1][r]), fmaxf(sc[2][r], sc[3][r]));
#pragma unroll
        for (int off = 1; off < 16; off <<= 1) mx = fmaxf(mx, __shfl_xor(mx, off));
        const float mnew = fmaxf(m_i[r], mx);
        alpha[r] = __expf(m_i[r] - mnew);
        m_i[r] = mnew;
        rsum[r] = 0.f;
      }
#pragma unroll
      for (int nt = 0; nt < 4; ++nt)
#pragma unroll
        for (int r = 0; r < 4; ++r) {
          const float p = __expf(sc[nt][r] - m_i[r]);
          rsum[r] += p;
          Pw[(g * 4 + r) * 76 + nt * 16 + l15] = p;
        }
#pragma unroll
      for (int r = 0; r < 4; ++r) {
#pragma unroll
        for (int off = 1; off < 16; off <<= 1) rsum[r] += __shfl_xor(rsum[r], off);
        l_i[r] = l_i[r] * alpha[r] + rsum[r];
      }
#pragma unroll
      for (int nt = 0; nt < 8; ++nt)
#pragma unroll
        for (int r = 0; r < 4; ++r) o[nt][r] *= alpha[r];

      // ---- P -> hi/lo bf16 A-frags (per-wave LDS round-trip, NO barrier) ----
      v8s ph[2], plo[2];
#pragma unroll
      for (int ks = 0; ks < 2; ++ks) {
        const float* pr = &Pw[l15 * 76 + ks * 32 + g * 8];
        const v4f pa = *(const v4f*)pr;
        const v4f pb = *(const v4f*)(pr + 4);
        const float pf[8] = {pa.x, pa.y, pa.z, pa.w, pb.x, pb.y, pb.z, pb.w};
#pragma unroll
        for (int j = 0; j < 8; ++j) {
          const unsigned short hb = bf16_rne(pf[j]);
          ph[ks][j] = (short)hb;
          plo[ks][j] = (short)bf16_rne(pf[j] - bf16f(hb));
        }
      }
      // ---- PV: bf16 MFMA, V direct from global vT[d][s] ----
#pragma unroll
      for (int nt = 0; nt < 8; ++nt) {
        const unsigned short* vp =
            vT + (size_t)(h * HDIM + nt * 16 + l15) * S_LEN + kt * 64 + g * 8;
        const v8s v0 = *(const v8s*)vp;
        const v8s v1 = *(const v8s*)(vp + 32);
        o[nt] = __builtin_amdgcn_mfma_f32_16x16x32_bf16(ph[0], v0, o[nt], 0, 0, 0);
        o[nt] = __builtin_amdgcn_mfma_f32_16x16x32_bf16(plo[0], v0, o[nt], 0, 0, 0);
        o[nt] = __builtin_amdgcn_mfma_f32_16x16x32_bf16(ph[1], v1, o[nt], 0, 0, 0);
        o[nt] = __builtin_amdgcn_mfma_f32_16x16x32_bf16(plo[1], v1, o[nt], 0, 0, 0);
      }
    }

    // ---- merge the 4 waves' (m, l, O) ----
    if (l15 == 0) {
#pragma unroll
      for (int r = 0; r < 4; ++r) {
        Ml[w * 16 + g * 4 + r] = m_i[r];
        Ll[w * 16 + g * 4 + r] = l_i[r];
      }
    }
    __syncthreads();  // (m,l) visible; all waves done with their Pst region
    float scale[4];
#pragma unroll
    for (int r = 0; r < 4; ++r) {
      const int row = g * 4 + r;
      float M = Ml[row];
      M = fmaxf(M, Ml[16 + row]);
      M = fmaxf(M, Ml[32 + row]);
      M = fmaxf(M, Ml[48 + row]);
      scale[r] = __expf(m_i[r] - M);  // 0 for idle waves (m=-inf)
    }
    float* Ol = smem;  // [w][16][132], aliases Pst (dead now)
#pragma unroll
    for (int nt = 0; nt < 8; ++nt)
#pragma unroll
      for (int r = 0; r < 4; ++r)
        Ol[(w * 16 + g * 4 + r) * 132 + nt * 16 + l15] = o[nt][r] * scale[r];
    __syncthreads();

    // final: each thread -> 8 consecutive d of one row
    const int row = t >> 4, dbase = (t & 15) * 8;
    float M = Ml[row];
    M = fmaxf(M, Ml[16 + row]);
    M = fmaxf(M, Ml[32 + row]);
    M = fmaxf(M, Ml[48 + row]);
    float L = 0.f;
#pragma unroll
    for (int ww = 0; ww < 4; ++ww) L += __expf(Ml[ww * 16 + row] - M) * Ll[ww * 16 + row];
    unsigned lo = 0, hi = 0;
#pragma unroll
    for (int j = 0; j < 8; ++j) {
      float res = 0.f;
#pragma unroll
      for (int ww = 0; ww < 4; ++ww) res += Ol[(ww * 16 + row) * 132 + dbase + j];
      // out = res*0.1/L, out_q = rint(out/0.1) clamp ±127  (0.1 cancels exactly)
      const int q = (int)fminf(fmaxf(rintf(res / L), -127.f), 127.f) & 0xff;
      if (j < 4) lo |= (unsigned)q << (8 * j);
      else       hi |= (unsigned)q << (8 * (j - 4));
    }
    *(int2*)(o8 + (size_t)(q0 + row) * D_DIM + h * HDIM + dbase) =
        make_int2((int)lo, (int)hi);
    __syncthreads();  // smem (Ol/Ml/Ll) dead before next item reuses it
  }
}

// ---------------------------------------------------------------------------
extern "C" void kernel_launch(void* const* d_in, const int* in_sizes, int n_in,
                              void* d_out, int out_size, void* d_ws, size_t ws_size,
                              hipStream_t stream) {
  (void)in_sizes; (void)n_in; (void)out_size; (void)ws_size;
  const float* hidden = (const float*)d_in[0];
  const float* wq = (const float*)d_in[1];
  const float* wk = (const float*)d_in[2];
  const float* wv = (const float*)d_in[3];
  const float* wo = (const float*)d_in[4];
  const float* sq = (const float*)d_in[5];
  const float* sk = (const float*)d_in[6];
  const float* sv = (const float*)d_in[7];
  const float* so = (const float*)d_in[8];
  // d_in[9] = attention_mask (pure causal; handled analytically)
  const int* pos = (const int*)d_in[10];
  float* out = (float*)d_out;

  char* ws = (char*)d_ws;
  int8_t* h8 = (int8_t*)ws;                                   // 8 MB (later o8)
  int8_t* q8 = (int8_t*)(ws + (8ull << 20));                  // 8 MB
  int8_t* k8 = (int8_t*)(ws + (16ull << 20));                 // 8 MB
  unsigned short* vT = (unsigned short*)(ws + (24ull << 20)); // 16 MB bf16 [D][S]
  int8_t* w8a = (int8_t*)(ws + (40ull << 20));                // 16 MB (wq, later wo)
  int8_t* w8b = (int8_t*)(ws + (56ull << 20));                // 16 MB (wk)
  int8_t* w8c = (int8_t*)(ws + (72ull << 20));                // 16 MB (wv)
  float* ctab = (float*)(ws + (88ull << 20));                 // 512 KB
  float* stab = (float*)(ws + (88ull << 20) + (512ull << 10));
  int8_t* o8 = h8;  // h8 dead after v-GEMM; attn writes o8 there

  hipLaunchKernelGGL(rope_tab_k, dim3(512), dim3(256), 0, stream, pos, ctab, stab);
  hipLaunchKernelGGL(quant_hidden_k, dim3(8192), dim3(256), 0, stream, hidden, h8);
  // wq,wk,wv -> w8a|w8b|w8c (contiguous 48 MB) in one launch
  hipLaunchKernelGGL(wconv3_k, dim3(49152), dim3(256), 0, stream, wq, wk, wv, w8a);

  const dim3 gg(32, 16), gb(256);
  hipLaunchKernelGGL((gemm_i8<0>), gg, gb, 0, stream, h8, w8a, sq, ctab, stab, (void*)q8);
  hipLaunchKernelGGL((gemm_i8<1>), gg, gb, 0, stream, h8, w8b, sk, ctab, stab, (void*)k8);
  hipLaunchKernelGGL((gemm_i8<2>), gg, gb, 0, stream, h8, w8c, sv, ctab, stab, (void*)vT);
  hipLaunchKernelGGL(wconv_k, dim3(16384), dim3(256), 0, stream, wo, w8a);  // wq dead
  hipLaunchKernelGGL(attn_mfma, dim3(32, 32), dim3(256), 0, stream, q8, k8, vT, o8);
  hipLaunchKernelGGL((gemm_i8<3>), gg, gb, 0, stream, o8, w8a, so, ctab, stab, (void*)out);
}

// Round 5
// 667.654 us; speedup vs baseline: 15.3373x; 1.0206x over previous
//
#include <hip/hip_runtime.h>
#include <math.h>
#include <stdint.h>

#define S_LEN 2048
#define D_DIM 4096
#define NHEAD 32
#define HDIM  128

typedef int      v4i __attribute__((ext_vector_type(4)));
typedef float    v4f __attribute__((ext_vector_type(4)));
typedef _Float16 v8h __attribute__((ext_vector_type(8)));

__device__ __forceinline__ float quant128(float x) {
  return fminf(fmaxf(rintf(x / 0.1f), -128.f), 127.f);
}
// async 16B global->LDS DMA; LDS side is wave-uniform base + lane*16
__device__ __forceinline__ void gl_lds16(const void* g, void* l) {
  __builtin_amdgcn_global_load_lds(
      (const __attribute__((address_space(1))) void*)g,
      (__attribute__((address_space(3))) void*)l, 16, 0, 0);
}

// ---------------- prep kernels ----------------
__global__ __launch_bounds__(256) void quant_hidden_k(const float* __restrict__ in,
                                                      int8_t* __restrict__ out) {
  const int idx = blockIdx.x * 256 + threadIdx.x;
  const float4 v = ((const float4*)in)[idx];
  const int q0 = (int)quant128(v.x), q1 = (int)quant128(v.y);
  const int q2 = (int)quant128(v.z), q3 = (int)quant128(v.w);
  ((int*)out)[idx] = (q0 & 0xff) | ((q1 & 0xff) << 8) | ((q2 & 0xff) << 16) | ((q3 & 0xff) << 24);
}

// fused f32->int8 convert of wq,wk,wv into one contiguous 48MB dst
__global__ __launch_bounds__(256) void wconv3_k(const float* __restrict__ a,
                                                const float* __restrict__ b,
                                                const float* __restrict__ c,
                                                int8_t* __restrict__ out) {
  const int which = blockIdx.x >> 14;
  const int sub = blockIdx.x & 16383;
  const float* src = (which == 0) ? a : (which == 1) ? b : c;
  const int idx = sub * 256 + threadIdx.x;
  const float4 v = ((const float4*)src)[idx];  // int4-valued floats, exact
  const int q0 = __float2int_rn(v.x), q1 = __float2int_rn(v.y);
  const int q2 = __float2int_rn(v.z), q3 = __float2int_rn(v.w);
  ((int*)out)[(size_t)which * 4194304 + idx] =
      (q0 & 0xff) | ((q1 & 0xff) << 8) | ((q2 & 0xff) << 16) | ((q3 & 0xff) << 24);
}

__global__ __launch_bounds__(256) void wconv_k(const float* __restrict__ in,
                                               int8_t* __restrict__ out) {
  const int idx = blockIdx.x * 256 + threadIdx.x;
  const float4 v = ((const float4*)in)[idx];
  const int q0 = __float2int_rn(v.x), q1 = __float2int_rn(v.y);
  const int q2 = __float2int_rn(v.z), q3 = __float2int_rn(v.w);
  ((int*)out)[idx] = (q0 & 0xff) | ((q1 & 0xff) << 8) | ((q2 & 0xff) << 16) | ((q3 & 0xff) << 24);
}

__global__ __launch_bounds__(256) void rope_tab_k(const int* __restrict__ pos,
                                                  float* __restrict__ ct,
                                                  float* __restrict__ st) {
  const int idx = blockIdx.x * 256 + threadIdx.x;  // [S][64]
  const int s = idx >> 6, j = idx & 63;
  const float inv = exp2f((float)j * -0.20762050593046016f);  // 10000^(-j/64)
  const float a = (float)pos[s] * inv;
  float si, c;
  sincosf(a, &si, &c);
  ct[idx] = c;
  st[idx] = si;
}

// ---------------------------------------------------------------------------
// int8 MFMA GEMM v3: BK=128 (32 MFMA/wave per barrier-pair, half the drains),
// global_load_lds staging with XOR-swizzled rows (chunk c of row r lives at
// LDS chunk c^(r&7); frag reads then 2-way bank-aliased = free). Flat grid
// 512 with 4x4 tile-group swizzle so consecutively-dispatched blocks share
// A/B tiles in L2.
// ---------------------------------------------------------------------------
template <int OMODE>
__global__ __launch_bounds__(256) void gemm_i8(
    const int8_t* __restrict__ A8, const int8_t* __restrict__ W8,
    const float* __restrict__ wsc, const float* __restrict__ ctab,
    const float* __restrict__ stab, void* __restrict__ outp) {
  __shared__ __align__(16) int8_t Als[16384];  // 128 rows x 128 B
  __shared__ __align__(16) int8_t Bls[16384];
  const int t = threadIdx.x;
  const int w = t >> 6, lane = t & 63, g = lane >> 4, l15 = lane & 15;
  // 4x4 tile-group swizzle: 16 consecutive block IDs cover a 4x4 tile square
  const int G = blockIdx.x;
  const int within = G & 15, g16 = G >> 4;
  const int bn = ((g16 & 7) * 4 + (within & 3)) * 128;   // 32 n-tiles
  const int bm = ((g16 >> 3) * 4 + (within >> 2)) * 128; // 16 m-tiles

  // staging: wave w owns rows w*32 .. w*32+31 (4 DMA instrs x 8 rows each).
  const int srow = lane >> 3;                       // row within 8-row segment
  const int schunk = ((lane & 7) ^ srow) * 16;      // source chunk swizzle
  const int8_t* sA[4];
  const int8_t* sB[4];
  int8_t* dA[4];
  int8_t* dB[4];
#pragma unroll
  for (int i = 0; i < 4; ++i) {
    const int row = w * 32 + i * 8 + srow;
    sA[i] = A8 + (size_t)(bm + row) * D_DIM + schunk;
    sB[i] = W8 + (size_t)(bn + row) * D_DIM + schunk;
    dA[i] = Als + w * 4096 + i * 1024;
    dB[i] = Bls + w * 4096 + i * 1024;
  }

  v4i acc[8][2];
#pragma unroll
  for (int i = 0; i < 8; ++i) {
    acc[i][0] = (v4i){0, 0, 0, 0};
    acc[i][1] = (v4i){0, 0, 0, 0};
  }

  for (int k0 = 0; k0 < D_DIM; k0 += 128) {
#pragma unroll
    for (int i = 0; i < 4; ++i) {
      gl_lds16(sA[i] + k0, dA[i]);
      gl_lds16(sB[i] + k0, dB[i]);
    }
    __syncthreads();  // vmcnt drained before frag reads
#pragma unroll
    for (int kk = 0; kk < 2; ++kk) {
      const int coff = (((kk << 2) | g) ^ (l15 & 7)) * 16;
      const v4i bf0 = *(const v4i*)(Bls + (w * 16 + l15) * 128 + coff);
      const v4i bf1 = *(const v4i*)(Bls + (w * 16 + 64 + l15) * 128 + coff);
#pragma unroll
      for (int mi = 0; mi < 8; ++mi) {
        const v4i af = *(const v4i*)(Als + (mi * 16 + l15) * 128 + coff);
        acc[mi][0] = __builtin_amdgcn_mfma_i32_16x16x64_i8(af, bf0, acc[mi][0], 0, 0, 0);
        acc[mi][1] = __builtin_amdgcn_mfma_i32_16x16x64_i8(af, bf1, acc[mi][1], 0, 0, 0);
      }
    }
    __syncthreads();  // reads done before next DMA overwrites
  }

  if (OMODE == 0 || OMODE == 1) {
    const int jcol = w * 16 + l15;  // 0..63 (head spans the 128-col tile)
    const float sc0 = 0.1f * wsc[bn + jcol];
    const float sc1 = 0.1f * wsc[bn + jcol + 64];
    int8_t* dst = (int8_t*)outp;
#pragma unroll
    for (int mi = 0; mi < 8; ++mi) {
#pragma unroll
      for (int r = 0; r < 4; ++r) {
        const int s = bm + mi * 16 + g * 4 + r;
        const float c = ctab[s * 64 + jcol];
        const float si = stab[s * 64 + jcol];
        const float x1 = (float)acc[mi][0][r] * sc0;
        const float x2 = (float)acc[mi][1][r] * sc1;
        dst[(size_t)s * D_DIM + bn + jcol] = (int8_t)quant128(x1 * c - x2 * si);
        dst[(size_t)s * D_DIM + bn + jcol + 64] = (int8_t)quant128(x2 * c + x1 * si);
      }
    }
  } else if (OMODE == 2) {
    _Float16* dst = (_Float16*)outp;  // quantized V value (int <=128, exact in f16)
#pragma unroll
    for (int jt = 0; jt < 2; ++jt) {
      const int col = bn + w * 16 + jt * 64 + l15;
      const float scv = 0.1f * wsc[col];
#pragma unroll
      for (int mi = 0; mi < 8; ++mi) {
#pragma unroll
        for (int r = 0; r < 4; ++r) {
          const int s = bm + mi * 16 + g * 4 + r;
          dst[(size_t)col * S_LEN + s] = (_Float16)quant128((float)acc[mi][jt][r] * scv);
        }
      }
    }
  } else {
    float* dst = (float*)outp;
#pragma unroll
    for (int jt = 0; jt < 2; ++jt) {
      const int col = bn + w * 16 + jt * 64 + l15;
      const float scv = 0.1f * wsc[col];
#pragma unroll
      for (int mi = 0; mi < 8; ++mi) {
#pragma unroll
        for (int r = 0; r < 4; ++r) {
          const int s = bm + mi * 16 + g * 4 + r;
          dst[(size_t)s * D_DIM + col] = (float)acc[mi][jt][r] * scv;
        }
      }
    }
  }
}

// ---------------------------------------------------------------------------
// Flash attention v4. Grid (32,32): block (i,h) handles qt in
// {127-i, 64+i, 63-i, i} (uniform 66 key-tiles per block). Waves split key
// tiles; barrier-free K loop. Changes vs v3:
//  - P in single f16 (err 2^-11): PV MFMA halved, cvt = plain v_cvt_f16_f32.
//  - softmax denominator from the SAME f16 P via ones-column MFMA (lacc):
//    numerator/denominator errors track; no sum-shuffles.
//  - two-phase merge: LDS 34->20 KB.
// ---------------------------------------------------------------------------
__global__ __launch_bounds__(256) void attn_mfma(
    const int8_t* __restrict__ q8, const int8_t* __restrict__ k8,
    const _Float16* __restrict__ vT, int8_t* __restrict__ o8) {
  const int i = blockIdx.x;
  const int h = blockIdx.y;
  const int t = threadIdx.x;
  const int w = t >> 6, lane = t & 63, g = lane >> 4, l15 = lane & 15;

  // Pst[4][16][76] f32 (19456 B) aliased by merge Ol[64][68] f32 (17408 B)
  __shared__ __align__(16) float smem[4 * 16 * 76 + 128];
  float* Pw = smem + w * 16 * 76;
  float* Ml = smem + 4 * 16 * 76;
  float* Ll = Ml + 64;
  const float SSCALE = 8.838834764831845e-4f;  // 0.01 / sqrt(128)
  const v8h vones = {(_Float16)1, (_Float16)1, (_Float16)1, (_Float16)1,
                     (_Float16)1, (_Float16)1, (_Float16)1, (_Float16)1};

  const int qlist[4] = {127 - i, 64 + i, 63 - i, i};

  for (int it = 0; it < 4; ++it) {
    const int qt = qlist[it];
    const int q0 = qt * 16;
    const int T = (qt >> 2) + 1;  // number of 64-key tiles

    const v4i qa0 = *(const v4i*)(q8 + (size_t)(q0 + l15) * D_DIM + h * HDIM + g * 16);
    const v4i qa1 = *(const v4i*)(q8 + (size_t)(q0 + l15) * D_DIM + h * HDIM + 64 + g * 16);

    v4f o[8];
#pragma unroll
    for (int n = 0; n < 8; ++n) o[n] = (v4f){0.f, 0.f, 0.f, 0.f};
    v4f lacc = (v4f){0.f, 0.f, 0.f, 0.f};  // row-sums of f16 P via ones-MFMA
    float m_i[4] = {-INFINITY, -INFINITY, -INFINITY, -INFINITY};

    for (int kt = w; kt < T; kt += 4) {
      // ---- scores: int8 MFMA (exact int32) ----
      v4i s32[4];
#pragma unroll
      for (int nt = 0; nt < 4; ++nt) {
        const int key = kt * 64 + nt * 16 + l15;
        const v4i kb0 = *(const v4i*)(k8 + (size_t)key * D_DIM + h * HDIM + g * 16);
        const v4i kb1 = *(const v4i*)(k8 + (size_t)key * D_DIM + h * HDIM + 64 + g * 16);
        v4i c = (v4i){0, 0, 0, 0};
        c = __builtin_amdgcn_mfma_i32_16x16x64_i8(qa0, kb0, c, 0, 0, 0);
        c = __builtin_amdgcn_mfma_i32_16x16x64_i8(qa1, kb1, c, 0, 0, 0);
        s32[nt] = c;
      }
      float sc[4][4];
#pragma unroll
      for (int nt = 0; nt < 4; ++nt)
#pragma unroll
        for (int r = 0; r < 4; ++r) {
          float s = (float)s32[nt][r] * SSCALE;
          if (kt == T - 1) {  // only the last tile can cross the diagonal
            const int key = kt * 64 + nt * 16 + l15;
            const int q = q0 + g * 4 + r;
            if (key > q) s = -1.0e30f;
          }
          sc[nt][r] = s;
        }
      // ---- online softmax max + rescale ----
      float alpha[4];
#pragma unroll
      for (int r = 0; r < 4; ++r) {
        float mx = fmaxf(fmaxf(sc[0][r], sc[1][r]), fmaxf(sc[2][r], sc[3][r]));
#pragma unroll
        for (int off = 1; off < 16; off <<= 1) mx = fmaxf(mx, __shfl_xor(mx, off));
        const float mnew = fmaxf(m_i[r], mx);
        alpha[r] = __expf(m_i[r] - mnew);
        m_i[r] = mnew;
      }
#pragma unroll
      for (int nt = 0; nt < 4; ++nt)
#pragma unroll
        for (int r = 0; r < 4; ++r)
          Pw[(g * 4 + r) * 76 + nt * 16 + l15] = __expf(sc[nt][r] - m_i[r]);
#pragma unroll
      for (int nt = 0; nt < 8; ++nt)
#pragma unroll
        for (int r = 0; r < 4; ++r) o[nt][r] *= alpha[r];
#pragma unroll
      for (int r = 0; r < 4; ++r) lacc[r] *= alpha[r];

      // ---- P -> f16 A-frags (per-wave LDS round-trip, no barrier) ----
      v8h ph0, ph1;
      {
        const float* pr = &Pw[l15 * 76 + g * 8];
        const v4f pa = *(const v4f*)pr;
        const v4f pb = *(const v4f*)(pr + 4);
        const v4f pc = *(const v4f*)(pr + 32);
        const v4f pd = *(const v4f*)(pr + 36);
#pragma unroll
        for (int j = 0; j < 4; ++j) {
          ph0[j] = (_Float16)pa[j];
          ph0[4 + j] = (_Float16)pb[j];
          ph1[j] = (_Float16)pc[j];
          ph1[4 + j] = (_Float16)pd[j];
        }
      }
      // denominator rides on the MFMA pipe (B = ones)
      lacc = __builtin_amdgcn_mfma_f32_16x16x32_f16(ph0, vones, lacc, 0, 0, 0);
      lacc = __builtin_amdgcn_mfma_f32_16x16x32_f16(ph1, vones, lacc, 0, 0, 0);
      // ---- PV: f16 MFMA, V direct from global vT[d][s] f16 ----
#pragma unroll
      for (int nt = 0; nt < 8; ++nt) {
        const _Float16* vp =
            vT + (size_t)(h * HDIM + nt * 16 + l15) * S_LEN + kt * 64 + g * 8;
        const v8h v0 = *(const v8h*)vp;
        const v8h v1 = *(const v8h*)(vp + 32);
        o[nt] = __builtin_amdgcn_mfma_f32_16x16x32_f16(ph0, v0, o[nt], 0, 0, 0);
        o[nt] = __builtin_amdgcn_mfma_f32_16x16x32_f16(ph1, v1, o[nt], 0, 0, 0);
      }
    }

    // ---- merge the 4 waves' (m, l, O); two phases of 64 d ----
    if (l15 == 0) {
#pragma unroll
      for (int r = 0; r < 4; ++r) {
        Ml[w * 16 + g * 4 + r] = m_i[r];
        Ll[w * 16 + g * 4 + r] = lacc[r];
      }
    }
    __syncthreads();
    float scale[4];
#pragma unroll
    for (int r = 0; r < 4; ++r) {
      const int row = g * 4 + r;
      float M = fmaxf(fmaxf(Ml[row], Ml[16 + row]), fmaxf(Ml[32 + row], Ml[48 + row]));
      scale[r] = __expf(m_i[r] - M);  // 0 for idle waves (m=-inf)
    }
    float* Ol = smem;  // [4 waves][16 rows][68], aliases Pst (dead now)
    const int row = t >> 4, db4 = (t & 15) * 4;  // reduce mapping
#pragma unroll
    for (int ph = 0; ph < 2; ++ph) {
#pragma unroll
      for (int nt = 0; nt < 4; ++nt)
#pragma unroll
        for (int r = 0; r < 4; ++r)
          Ol[(w * 16 + g * 4 + r) * 68 + nt * 16 + l15] = o[ph * 4 + nt][r] * scale[r];
      __syncthreads();
      // reduce: thread -> (row, 4 d) of this 64-d phase
      float M = fmaxf(fmaxf(Ml[row], Ml[16 + row]), fmaxf(Ml[32 + row], Ml[48 + row]));
      float L = 0.f;
#pragma unroll
      for (int ww = 0; ww < 4; ++ww)
        L += __expf(Ml[ww * 16 + row] - M) * Ll[ww * 16 + row];
      unsigned pk = 0;
#pragma unroll
      for (int j = 0; j < 4; ++j) {
        float res = 0.f;
#pragma unroll
        for (int ww = 0; ww < 4; ++ww) res += Ol[(ww * 16 + row) * 68 + db4 + j];
        // out = res*0.1/L; out_q = rint(out/0.1) clamp +-127 (0.1 cancels)
        const int q = (int)fminf(fmaxf(rintf(res / L), -127.f), 127.f) & 0xff;
        pk |= (unsigned)q << (8 * j);
      }
      *(int*)(o8 + (size_t)(q0 + row) * D_DIM + h * HDIM + ph * 64 + db4) = (int)pk;
      __syncthreads();  // Ol reads done before next phase / next item
    }
  }
}

// ---------------------------------------------------------------------------
extern "C" void kernel_launch(void* const* d_in, const int* in_sizes, int n_in,
                              void* d_out, int out_size, void* d_ws, size_t ws_size,
                              hipStream_t stream) {
  (void)in_sizes; (void)n_in; (void)out_size; (void)ws_size;
  const float* hidden = (const float*)d_in[0];
  const float* wq = (const float*)d_in[1];
  const float* wk = (const float*)d_in[2];
  const float* wv = (const float*)d_in[3];
  const float* wo = (const float*)d_in[4];
  const float* sq = (const float*)d_in[5];
  const float* sk = (const float*)d_in[6];
  const float* sv = (const float*)d_in[7];
  const float* so = (const float*)d_in[8];
  // d_in[9] = attention_mask (pure causal; handled analytically)
  const int* pos = (const int*)d_in[10];
  float* out = (float*)d_out;

  char* ws = (char*)d_ws;
  int8_t* h8 = (int8_t*)ws;                                   // 8 MB (later o8)
  int8_t* q8 = (int8_t*)(ws + (8ull << 20));                  // 8 MB
  int8_t* k8 = (int8_t*)(ws + (16ull << 20));                 // 8 MB
  _Float16* vT = (_Float16*)(ws + (24ull << 20));             // 16 MB f16 [D][S]
  int8_t* w8a = (int8_t*)(ws + (40ull << 20));                // 16 MB (wq, later wo)
  int8_t* w8b = (int8_t*)(ws + (56ull << 20));                // 16 MB (wk)
  int8_t* w8c = (int8_t*)(ws + (72ull << 20));                // 16 MB (wv)
  float* ctab = (float*)(ws + (88ull << 20));                 // 512 KB
  float* stab = (float*)(ws + (88ull << 20) + (512ull << 10));
  int8_t* o8 = h8;  // h8 dead after v-GEMM; attn writes o8 there

  hipLaunchKernelGGL(rope_tab_k, dim3(512), dim3(256), 0, stream, pos, ctab, stab);
  hipLaunchKernelGGL(quant_hidden_k, dim3(8192), dim3(256), 0, stream, hidden, h8);
  hipLaunchKernelGGL(wconv3_k, dim3(49152), dim3(256), 0, stream, wq, wk, wv, w8a);

  const dim3 gg(512), gb(256);
  hipLaunchKernelGGL((gemm_i8<0>), gg, gb, 0, stream, h8, w8a, sq, ctab, stab, (void*)q8);
  hipLaunchKernelGGL((gemm_i8<1>), gg, gb, 0, stream, h8, w8b, sk, ctab, stab, (void*)k8);
  hipLaunchKernelGGL((gemm_i8<2>), gg, gb, 0, stream, h8, w8c, sv, ctab, stab, (void*)vT);
  hipLaunchKernelGGL(wconv_k, dim3(16384), dim3(256), 0, stream, wo, w8a);  // wq dead
  hipLaunchKernelGGL(attn_mfma, dim3(32, 32), dim3(256), 0, stream, q8, k8, vT, o8);
  hipLaunchKernelGGL((gemm_i8<3>), gg, gb, 0, stream, o8, w8a, so, ctab, stab, (void*)out);
}